// Round 8
// baseline (41.129 us; speedup 1.0000x reference)
//
#include <hip/hip_runtime.h>
#include <math.h>

#define N_BOIDS 8192
typedef float f32x2 __attribute__((ext_vector_type(2)));
typedef float f32x4 __attribute__((ext_vector_type(4)));

// ---- binning parameters
constexpr int   NC     = 16;          // cells per axis
constexpr int   NCELL  = NC * NC;     // 256
constexpr float MARG   = 0.2002f;     // perception radius + f32-rounding slack
constexpr int   CHUNK  = 256;         // boids per sort block
constexpr int   NBLK   = N_BOIDS / CHUNK;  // 32
// ws layout (bytes)
constexpr size_t HIST_OFF = 0;                       // 32*256*4 = 32768
constexpr size_t BASE_OFF = 32768;                   // 32768
constexpr size_t CS_OFF   = 65536;                   // 257*4 -> pad 4096
constexpr size_t SORT_OFF = 69632;                   // 8192*16 = 131072
constexpr size_t SIDX_OFF = 200704;                  // 32768
constexpr size_t WS_NEED  = 233472;

// f32 roundings of the Python doubles 0.02**2 and 0.2**2
constexpr float SEP_R2  = 4.0000000000000008e-04f;
constexpr float PERC_R2 = 4.0000000000000001e-02f;
constexpr float EPSF    = 1e-08f;

__device__ __forceinline__ int cell_of(float px, float py) {
    int cx = (int)(px * 16.0f); cx = cx > 15 ? 15 : (cx < 0 ? 0 : cx);
    int cy = (int)(py * 16.0f); cy = cy > 15 ? 15 : (cy < 0 ? 0 : cy);
    return cy * NC + cx;
}

// ---- sort kernel A: per-chunk cell histogram (deterministic: int atomics)
__global__ __launch_bounds__(CHUNK) void cell_hist(
    const float* __restrict__ pos, int* __restrict__ hist)
{
    __shared__ int h[NCELL];
    const int tid = threadIdx.x;
    h[tid] = 0;
    __syncthreads();
    const int i = blockIdx.x * CHUNK + tid;
    atomicAdd(&h[cell_of(pos[2 * i], pos[2 * i + 1])], 1);
    __syncthreads();
    hist[blockIdx.x * NCELL + tid] = h[tid];
}

// ---- sort kernel B: cell starts + per-(chunk,cell) bases
__global__ __launch_bounds__(NCELL) void cell_scan(
    const int* __restrict__ hist, int* __restrict__ base, int* __restrict__ cs)
{
    __shared__ int tot[NCELL];
    __shared__ int sc[NCELL + 1];
    const int c = threadIdx.x;
    int hh[NBLK];
    int t = 0;
#pragma unroll
    for (int b = 0; b < NBLK; ++b) { hh[b] = hist[b * NCELL + c]; t += hh[b]; }
    tot[c] = t;
    __syncthreads();
    if (c == 0) {
        int run = 0;
        for (int k = 0; k < NCELL; ++k) { sc[k] = run; run += tot[k]; }
        sc[NCELL] = run;
    }
    __syncthreads();
    cs[c] = sc[c];
    if (c == 0) cs[NCELL] = sc[NCELL];
    int run2 = sc[c];
#pragma unroll
    for (int b = 0; b < NBLK; ++b) { base[b * NCELL + c] = run2; run2 += hh[b]; }
}

// ---- sort kernel C: stable scatter (order = (cell, chunk, tid) — deterministic)
__global__ __launch_bounds__(CHUNK) void cell_scatter(
    const float* __restrict__ pos, const float* __restrict__ vel,
    const int* __restrict__ base, float4* __restrict__ sorted4,
    int* __restrict__ sidx)
{
    __shared__ int cid[CHUNK];
    __shared__ int lbase[NCELL];
    const int tid = threadIdx.x;
    const int b   = blockIdx.x;
    const int i   = b * CHUNK + tid;
    const float px = pos[2 * i], py = pos[2 * i + 1];
    const int c = cell_of(px, py);
    cid[tid]   = c;
    lbase[tid] = base[b * NCELL + tid];
    __syncthreads();
    int rank = 0;
    for (int t2 = 0; t2 < tid; ++t2) rank += (cid[t2] == c) ? 1 : 0;
    const int slot = lbase[c] + rank;
    float4 o; o.x = px; o.y = py; o.z = vel[2 * i]; o.w = vel[2 * i + 1];
    sorted4[slot] = o;
    sidx[slot]    = i;
}

__device__ __forceinline__ void finalize_core(
    float vix, float viy, const f32x2 nz,
    float ws, float wa, float wc, float wn,
    float sx, float sy, float vx, float vy, float cx, float cy, float cntall,
    float* __restrict__ out, int orig)
{
    const float cnt = cntall - 1.0f;  // remove self (d2==0 passed the mask)
    float ns  = fmaxf(sqrtf(sx * sx + sy * sy), EPSF);
    float ssx = sx / ns, ssy = sy / ns;
    float vax = (vx - vix) / cnt - vix;
    float vay = (vy - viy) / cnt - viy;
    float na  = fmaxf(sqrtf(vax * vax + vay * vay), EPSF);
    float sax = vax / na, say = vay / na;
    float pax = cx / cnt, pay = cy / cnt;
    float nc  = fmaxf(sqrtf(pax * pax + pay * pay), EPSF);
    float scx = pax / nc, scy = pay / nc;
    float ax = ws * ssx + wa * sax + wc * scx;
    float ay = ws * ssy + wa * say + wc * scy;
    ax += wn * nz.x;
    ay += wn * nz.y;
    const float nn = sqrtf(ax * ax + ay * ay);
    if (nn > 1.0f) {
        const float s = 1.0f / fmaxf(nn, EPSF);
        ax *= s;
        ay *= s;
    }
    out[2 * orig]     = ax;
    out[2 * orig + 1] = ay;
}

// ---- main kernel: 2 sorted i-boids per wave, neighborhood-limited j loop
__global__ __launch_bounds__(256, 4) void boids_main(
    const float4* __restrict__ sorted4,
    const int* __restrict__ sidx,
    const int* __restrict__ cs,
    const f32x2* __restrict__ noise,
    const float* __restrict__ w_sep,
    const float* __restrict__ w_ali,
    const float* __restrict__ w_coh,
    const float* __restrict__ w_noise,
    float* __restrict__ out)
{
    __shared__ int cs_l[NCELL + 1];
    const int tid = threadIdx.x;
    cs_l[tid] = cs[tid];
    if (tid == 0) cs_l[NCELL] = cs[NCELL];
    __syncthreads();

    const int lane = tid & 63;
    const int wid  = tid >> 6;
    const int i0   = (blockIdx.x * 4 + wid) * 2;

    const float4 I0 = sorted4[i0];
    const float4 I1 = sorted4[i0 + 1];
    const float vperc = PERC_R2;
    const float vsep  = SEP_R2;

    // union perception box of the two i-boids -> cell ranges (wrap via &15)
    const float xmn = fminf(I0.x, I1.x), xmx = fmaxf(I0.x, I1.x);
    const float ymn = fminf(I0.y, I1.y), ymx = fmaxf(I0.y, I1.y);
    const int cx0 = (int)floorf((xmn - MARG) * 16.0f);
    const int cx1 = (int)floorf((xmx + MARG) * 16.0f);
    const int cy0 = (int)floorf((ymn - MARG) * 16.0f);
    const int cy1 = (int)floorf((ymx + MARG) * 16.0f);
    int nx = cx1 - cx0 + 1; if (nx > NC) nx = NC;
    int ny = cy1 - cy0 + 1; if (ny > NC) ny = NC;

    float n0 = 0.f, s0x = 0.f, s0y = 0.f, v0x = 0.f, v0y = 0.f, c0x = 0.f, c0y = 0.f;
    float n1 = 0.f, s1x = 0.f, s1y = 0.f, v1x = 0.f, v1y = 0.f, c1x = 0.f, c1y = 0.f;

    for (int r = 0; r < ny; ++r) {
        const int ry      = (cy0 + r) & (NC - 1);
        const int rowbase = ry * NC;
        const int a0      = cx0 & (NC - 1);
        const int lenA    = (nx < NC - a0) ? nx : (NC - a0);
        const int lenB    = nx - lenA;
        const int sA = cs_l[rowbase + a0];
        const int eA = cs_l[rowbase + a0 + lenA];
        const int sB = cs_l[rowbase];
        const int eB = cs_l[rowbase + lenB];   // lenB==0 -> sB==eB -> skipped
        for (int seg = 0; seg < 2; ++seg) {
            const int js = seg ? sB : sA;
            const int je = seg ? eB : eA;
            for (int j0 = js; j0 < je; j0 += 64) {
                const int   rem = je - j0;
                const int   jj  = (lane < rem) ? (j0 + lane) : j0;
                const float inv = (lane < rem) ? 0.0f : 1e9f;  // kills masks on pad lanes
                const float4 q  = sorted4[jj];
                float dx0, dy0, dx1, dy1, ta, tb, tc, m;
                asm(
                    "v_sub_f32   %[dx0], %[qx], %[p0x]\n\t"
                    "v_sub_f32   %[dy0], %[qy], %[p0y]\n\t"
                    "v_sub_f32   %[dx1], %[qx], %[p1x]\n\t"
                    "v_sub_f32   %[dy1], %[qy], %[p1y]\n\t"
                    "v_rndne_f32 %[ta], %[dx0]\n\t"
                    "v_rndne_f32 %[tb], %[dy0]\n\t"
                    "v_sub_f32   %[dx0], %[dx0], %[ta]\n\t"
                    "v_sub_f32   %[dy0], %[dy0], %[tb]\n\t"
                    "v_rndne_f32 %[ta], %[dx1]\n\t"
                    "v_rndne_f32 %[tb], %[dy1]\n\t"
                    "v_sub_f32   %[dx1], %[dx1], %[ta]\n\t"
                    "v_sub_f32   %[dy1], %[dy1], %[tb]\n\t"
                    "v_mul_f32   %[ta], %[dx0], %[dx0]\n\t"
                    "v_mul_f32   %[tb], %[dy0], %[dy0]\n\t"
                    "v_add_f32   %[ta], %[ta], %[tb]\n\t"   // d2 boid0 (exact)
                    "v_max_f32   %[ta], %[ta], %[inv]\n\t"  // pad lanes -> 1e9
                    "v_mul_f32   %[tb], %[dx1], %[dx1]\n\t"
                    "v_mul_f32   %[tc], %[dy1], %[dy1]\n\t"
                    "v_add_f32   %[tb], %[tb], %[tc]\n\t"   // d2 boid1 (exact)
                    "v_max_f32   %[tb], %[tb], %[inv]\n\t"
                    // perception boid0
                    "v_cmp_ge_f32 vcc, %[vperc], %[ta]\n\t"
                    "v_cndmask_b32 %[m], 0, 1.0, vcc\n\t"
                    "v_add_f32   %[n0], %[n0], %[m]\n\t"
                    "v_fmac_f32  %[v0x], %[m], %[qz]\n\t"
                    "v_fmac_f32  %[v0y], %[m], %[qw]\n\t"
                    "v_fmac_f32  %[c0x], %[m], %[dx0]\n\t"
                    "v_fmac_f32  %[c0y], %[m], %[dy0]\n\t"
                    // perception boid1
                    "v_cmp_ge_f32 vcc, %[vperc], %[tb]\n\t"
                    "v_cndmask_b32 %[m], 0, 1.0, vcc\n\t"
                    "v_add_f32   %[n1], %[n1], %[m]\n\t"
                    "v_fmac_f32  %[v1x], %[m], %[qz]\n\t"
                    "v_fmac_f32  %[v1y], %[m], %[qw]\n\t"
                    "v_fmac_f32  %[c1x], %[m], %[dx1]\n\t"
                    "v_fmac_f32  %[c1y], %[m], %[dy1]\n\t"
                    // separation boid0
                    "v_cmp_ge_f32 vcc, %[vsep], %[ta]\n\t"
                    "v_cndmask_b32 %[m], 0, 1.0, vcc\n\t"
                    "v_fma_f32   %[s0x], -%[m], %[dx0], %[s0x]\n\t"
                    "v_fma_f32   %[s0y], -%[m], %[dy0], %[s0y]\n\t"
                    // separation boid1
                    "v_cmp_ge_f32 vcc, %[vsep], %[tb]\n\t"
                    "v_cndmask_b32 %[m], 0, 1.0, vcc\n\t"
                    "v_fma_f32   %[s1x], -%[m], %[dx1], %[s1x]\n\t"
                    "v_fma_f32   %[s1y], -%[m], %[dy1], %[s1y]\n\t"
                    : [dx0] "=&v"(dx0), [dy0] "=&v"(dy0),
                      [dx1] "=&v"(dx1), [dy1] "=&v"(dy1),
                      [ta] "=&v"(ta), [tb] "=&v"(tb), [tc] "=&v"(tc), [m] "=&v"(m),
                      [n0] "+v"(n0), [s0x] "+v"(s0x), [s0y] "+v"(s0y),
                      [v0x] "+v"(v0x), [v0y] "+v"(v0y),
                      [c0x] "+v"(c0x), [c0y] "+v"(c0y),
                      [n1] "+v"(n1), [s1x] "+v"(s1x), [s1y] "+v"(s1y),
                      [v1x] "+v"(v1x), [v1y] "+v"(v1y),
                      [c1x] "+v"(c1x), [c1y] "+v"(c1y)
                    : [qx] "v"(q.x), [qy] "v"(q.y), [qz] "v"(q.z), [qw] "v"(q.w),
                      [p0x] "v"(I0.x), [p0y] "v"(I0.y),
                      [p1x] "v"(I1.x), [p1y] "v"(I1.y),
                      [vperc] "v"(vperc), [vsep] "v"(vsep), [inv] "v"(inv)
                    : "vcc");
            }
        }
    }

    // full-wave butterfly reduction
#pragma unroll
    for (int mlev = 1; mlev < 64; mlev <<= 1) {
        n0  += __shfl_xor(n0,  mlev);
        s0x += __shfl_xor(s0x, mlev);  s0y += __shfl_xor(s0y, mlev);
        v0x += __shfl_xor(v0x, mlev);  v0y += __shfl_xor(v0y, mlev);
        c0x += __shfl_xor(c0x, mlev);  c0y += __shfl_xor(c0y, mlev);
        n1  += __shfl_xor(n1,  mlev);
        s1x += __shfl_xor(s1x, mlev);  s1y += __shfl_xor(s1y, mlev);
        v1x += __shfl_xor(v1x, mlev);  v1y += __shfl_xor(v1y, mlev);
        c1x += __shfl_xor(c1x, mlev);  c1y += __shfl_xor(c1y, mlev);
    }

    if (lane < 2) {
        float sx = s0x, sy = s0y, vx = v0x, vy = v0y, cx = c0x, cy = c0y, cc = n0;
        float vix = I0.z, viy = I0.w;
        if (lane == 1) {
            sx = s1x; sy = s1y; vx = v1x; vy = v1y; cx = c1x; cy = c1y; cc = n1;
            vix = I1.z; viy = I1.w;
        }
        const int orig = sidx[i0 + lane];
        finalize_core(vix, viy, noise[orig],
                      w_sep[0], w_ali[0], w_coh[0], w_noise[0],
                      sx, sy, vx, vy, cx, cy, cc, out, orig);
    }
}

// ================= fallback: proven R5 all-pairs kernel =================
constexpr int FB_BLOCK = 256;
constexpr int FB_TILE  = 2048;

__global__ __launch_bounds__(FB_BLOCK, 4) void boids_allpairs(
    const f32x2* __restrict__ pos, const f32x2* __restrict__ vel,
    const f32x2* __restrict__ noise,
    const float* __restrict__ w_sep, const float* __restrict__ w_ali,
    const float* __restrict__ w_coh, const float* __restrict__ w_noise,
    float* __restrict__ out)
{
    __shared__ f32x4 tile[FB_TILE];
    const int tid  = threadIdx.x;
    const int lane = tid & 63;
    const int wid  = tid >> 6;
    const int i0   = (blockIdx.x * 4 + wid) * 2;
    const f32x2 P0 = pos[i0];
    const f32x2 P1 = pos[i0 + 1];
    const float vperc = PERC_R2, vsep = SEP_R2;
    float n0 = 0.f, s0x = 0.f, s0y = 0.f, v0x = 0.f, v0y = 0.f, c0x = 0.f, c0y = 0.f;
    float n1 = 0.f, s1x = 0.f, s1y = 0.f, v1x = 0.f, v1y = 0.f, c1x = 0.f, c1y = 0.f;
    for (int t = 0; t < N_BOIDS / FB_TILE; ++t) {
        const f32x4* gp = reinterpret_cast<const f32x4*>(pos) + t * (FB_TILE / 2);
        const f32x4* gv = reinterpret_cast<const f32x4*>(vel) + t * (FB_TILE / 2);
#pragma unroll
        for (int c = 0; c < FB_TILE / 2 / FB_BLOCK; ++c) {
            const int idx  = tid + c * FB_BLOCK;
            const f32x4 pp = gp[idx];
            const f32x4 vv = gv[idx];
            f32x4 t0; t0.x = pp.x; t0.y = pp.y; t0.z = vv.x; t0.w = vv.y;
            f32x4 t1; t1.x = pp.z; t1.y = pp.w; t1.z = vv.z; t1.w = vv.w;
            tile[2 * idx] = t0; tile[2 * idx + 1] = t1;
        }
        __syncthreads();
#pragma unroll 8
        for (int k = 0; k < FB_TILE / 64; ++k) {
            const f32x4 q = tile[lane + k * 64];
            float dx, dy, ta, tb, m;
            asm("v_sub_f32 %[dx], %[qx], %[p0x]\n\t"
                "v_sub_f32 %[dy], %[qy], %[p0y]\n\t"
                "v_rndne_f32 %[ta], %[dx]\n\t"
                "v_rndne_f32 %[tb], %[dy]\n\t"
                "v_sub_f32 %[dx], %[dx], %[ta]\n\t"
                "v_sub_f32 %[dy], %[dy], %[tb]\n\t"
                "v_mul_f32 %[ta], %[dx], %[dx]\n\t"
                "v_mul_f32 %[tb], %[dy], %[dy]\n\t"
                "v_add_f32 %[ta], %[ta], %[tb]\n\t"
                "v_cmp_ge_f32 vcc, %[vperc], %[ta]\n\t"
                "v_cndmask_b32 %[m], 0, 1.0, vcc\n\t"
                "v_add_f32 %[n0], %[n0], %[m]\n\t"
                "v_fmac_f32 %[v0x], %[m], %[qz]\n\t"
                "v_fmac_f32 %[v0y], %[m], %[qw]\n\t"
                "v_fmac_f32 %[c0x], %[m], %[dx]\n\t"
                "v_fmac_f32 %[c0y], %[m], %[dy]\n\t"
                "v_cmp_ge_f32 vcc, %[vsep], %[ta]\n\t"
                "v_cndmask_b32 %[m], 0, 1.0, vcc\n\t"
                "v_fma_f32 %[s0x], -%[m], %[dx], %[s0x]\n\t"
                "v_fma_f32 %[s0y], -%[m], %[dy], %[s0y]\n\t"
                "v_sub_f32 %[dx], %[qx], %[p1x]\n\t"
                "v_sub_f32 %[dy], %[qy], %[p1y]\n\t"
                "v_rndne_f32 %[ta], %[dx]\n\t"
                "v_rndne_f32 %[tb], %[dy]\n\t"
                "v_sub_f32 %[dx], %[dx], %[ta]\n\t"
                "v_sub_f32 %[dy], %[dy], %[tb]\n\t"
                "v_mul_f32 %[ta], %[dx], %[dx]\n\t"
                "v_mul_f32 %[tb], %[dy], %[dy]\n\t"
                "v_add_f32 %[ta], %[ta], %[tb]\n\t"
                "v_cmp_ge_f32 vcc, %[vperc], %[ta]\n\t"
                "v_cndmask_b32 %[m], 0, 1.0, vcc\n\t"
                "v_add_f32 %[n1], %[n1], %[m]\n\t"
                "v_fmac_f32 %[v1x], %[m], %[qz]\n\t"
                "v_fmac_f32 %[v1y], %[m], %[qw]\n\t"
                "v_fmac_f32 %[c1x], %[m], %[dx]\n\t"
                "v_fmac_f32 %[c1y], %[m], %[dy]\n\t"
                "v_cmp_ge_f32 vcc, %[vsep], %[ta]\n\t"
                "v_cndmask_b32 %[m], 0, 1.0, vcc\n\t"
                "v_fma_f32 %[s1x], -%[m], %[dx], %[s1x]\n\t"
                "v_fma_f32 %[s1y], -%[m], %[dy], %[s1y]\n\t"
                : [dx] "=&v"(dx), [dy] "=&v"(dy), [ta] "=&v"(ta),
                  [tb] "=&v"(tb), [m] "=&v"(m),
                  [n0] "+v"(n0), [s0x] "+v"(s0x), [s0y] "+v"(s0y),
                  [v0x] "+v"(v0x), [v0y] "+v"(v0y), [c0x] "+v"(c0x), [c0y] "+v"(c0y),
                  [n1] "+v"(n1), [s1x] "+v"(s1x), [s1y] "+v"(s1y),
                  [v1x] "+v"(v1x), [v1y] "+v"(v1y), [c1x] "+v"(c1x), [c1y] "+v"(c1y)
                : [qx] "v"(q.x), [qy] "v"(q.y), [qz] "v"(q.z), [qw] "v"(q.w),
                  [p0x] "v"(P0.x), [p0y] "v"(P0.y),
                  [p1x] "v"(P1.x), [p1y] "v"(P1.y),
                  [vperc] "v"(vperc), [vsep] "v"(vsep)
                : "vcc");
        }
        __syncthreads();
    }
#pragma unroll
    for (int mlev = 1; mlev < 64; mlev <<= 1) {
        n0  += __shfl_xor(n0,  mlev);
        s0x += __shfl_xor(s0x, mlev);  s0y += __shfl_xor(s0y, mlev);
        v0x += __shfl_xor(v0x, mlev);  v0y += __shfl_xor(v0y, mlev);
        c0x += __shfl_xor(c0x, mlev);  c0y += __shfl_xor(c0y, mlev);
        n1  += __shfl_xor(n1,  mlev);
        s1x += __shfl_xor(s1x, mlev);  s1y += __shfl_xor(s1y, mlev);
        v1x += __shfl_xor(v1x, mlev);  v1y += __shfl_xor(v1y, mlev);
        c1x += __shfl_xor(c1x, mlev);  c1y += __shfl_xor(c1y, mlev);
    }
    if (lane < 2) {
        float sx = s0x, sy = s0y, vx = v0x, vy = v0y, cx = c0x, cy = c0y, cc = n0;
        int i = i0;
        if (lane == 1) {
            sx = s1x; sy = s1y; vx = v1x; vy = v1y; cx = c1x; cy = c1y; cc = n1;
            i = i0 + 1;
        }
        finalize_core(vel[i].x, vel[i].y, noise[i],
                      w_sep[0], w_ali[0], w_coh[0], w_noise[0],
                      sx, sy, vx, vy, cx, cy, cc, out, i);
    }
}

extern "C" void kernel_launch(void* const* d_in, const int* in_sizes, int n_in,
                              void* d_out, int out_size, void* d_ws, size_t ws_size,
                              hipStream_t stream) {
    const float* pos_f   = (const float*)d_in[0];
    const float* vel_f   = (const float*)d_in[1];
    const f32x2* noise   = (const f32x2*)d_in[2];
    const float* w_sep   = (const float*)d_in[3];
    const float* w_ali   = (const float*)d_in[4];
    const float* w_coh   = (const float*)d_in[5];
    const float* w_noise = (const float*)d_in[6];
    float* out = (float*)d_out;

    if (ws_size >= WS_NEED) {
        char* wsb = (char*)d_ws;
        int*    hist    = (int*)(wsb + HIST_OFF);
        int*    base    = (int*)(wsb + BASE_OFF);
        int*    cs      = (int*)(wsb + CS_OFF);
        float4* sorted4 = (float4*)(wsb + SORT_OFF);
        int*    sidx    = (int*)(wsb + SIDX_OFF);
        cell_hist<<<NBLK, CHUNK, 0, stream>>>(pos_f, hist);
        cell_scan<<<1, NCELL, 0, stream>>>(hist, base, cs);
        cell_scatter<<<NBLK, CHUNK, 0, stream>>>(pos_f, vel_f, base, sorted4, sidx);
        boids_main<<<N_BOIDS / 8, 256, 0, stream>>>(
            sorted4, sidx, cs, noise, w_sep, w_ali, w_coh, w_noise, out);
    } else {
        boids_allpairs<<<N_BOIDS / 8, FB_BLOCK, 0, stream>>>(
            (const f32x2*)pos_f, (const f32x2*)vel_f, noise,
            w_sep, w_ali, w_coh, w_noise, out);
    }
}

// Round 9
// 35.826 us; speedup vs baseline: 1.1480x; 1.1480x over previous
//
#include <hip/hip_runtime.h>
#include <math.h>

#define N_BOIDS 8192
typedef float f32x2 __attribute__((ext_vector_type(2)));
typedef float f32x4 __attribute__((ext_vector_type(4)));

// ---- binning parameters
constexpr int   NC     = 16;               // cells per axis
constexpr int   NCELL  = NC * NC;          // 256
constexpr float MARG   = 0.2002f;          // perception radius + f32 slack
constexpr int   CHUNK  = 256;              // boids per sort block
constexpr int   NBLK   = N_BOIDS / CHUNK;  // 32
// ws layout (bytes)
constexpr size_t HIST_OFF = 0;             // 32*256*4 = 32768
constexpr size_t CS_OFF   = 32768;         // 257*4, padded to 4096
constexpr size_t SORT_OFF = 36864;         // 8192*16 = 131072
constexpr size_t SIDX_OFF = 167936;        // 8192*4  = 32768
constexpr size_t WS_NEED  = 200704;

// f32 roundings of the Python doubles 0.02**2 and 0.2**2
constexpr float SEP_R2  = 4.0000000000000008e-04f;
constexpr float PERC_R2 = 4.0000000000000001e-02f;
constexpr float EPSF    = 1e-08f;

__device__ __forceinline__ int cell_of(float px, float py) {
    int cx = (int)(px * 16.0f); cx = cx > 15 ? 15 : (cx < 0 ? 0 : cx);
    int cy = (int)(py * 16.0f); cy = cy > 15 ? 15 : (cy < 0 ? 0 : cy);
    return cy * NC + cx;
}

// ---- sort kernel A: per-chunk cell histogram
__global__ __launch_bounds__(CHUNK) void cell_hist(
    const float* __restrict__ pos, int* __restrict__ hist)
{
    __shared__ int h[NCELL];
    const int tid = threadIdx.x;
    h[tid] = 0;
    __syncthreads();
    const int i = blockIdx.x * CHUNK + tid;
    atomicAdd(&h[cell_of(pos[2 * i], pos[2 * i + 1])], 1);
    __syncthreads();
    hist[blockIdx.x * NCELL + tid] = h[tid];
}

// ---- sort kernel B: fused scan + stable scatter
// Each block redundantly scans the global histogram (parallel Hillis-Steele),
// then scatters its own chunk. Order = (cell, chunk, tid): deterministic.
__global__ __launch_bounds__(CHUNK) void cell_scan_scatter(
    const float* __restrict__ pos, const float* __restrict__ vel,
    const int* __restrict__ hist, int* __restrict__ cs,
    float4* __restrict__ sorted4, int* __restrict__ sidx)
{
    __shared__ int tot[NCELL];     // per-cell totals -> inclusive scan
    __shared__ int lbase[NCELL];   // this chunk's base per cell
    __shared__ int cid[CHUNK];
    const int c = threadIdx.x;     // doubles as cell id and chunk-local tid
    const int b = blockIdx.x;

    // load full histogram column c; total + partial sum over chunks < b
    int t = 0, part = 0;
#pragma unroll
    for (int bb = 0; bb < NBLK; ++bb) {
        const int hv = hist[bb * NCELL + c];
        t += hv;
        if (bb < b) part += hv;
    }
    const int mytot = t;
    tot[c] = t;
    __syncthreads();
    // Hillis-Steele inclusive scan over 256 cells
#pragma unroll
    for (int off = 1; off < NCELL; off <<= 1) {
        int v = 0;
        if (c >= off) v = tot[c - off];
        __syncthreads();
        tot[c] += v;
        __syncthreads();
    }
    const int excl = tot[c] - mytot;       // exclusive prefix = cell start
    lbase[c] = excl + part;
    cs[c] = excl;                          // all blocks write same values
    if (c == NCELL - 1) cs[NCELL] = tot[NCELL - 1];

    // stable rank within (chunk, cell)
    const int i = b * CHUNK + c;
    const float px = pos[2 * i], py = pos[2 * i + 1];
    const int myc = cell_of(px, py);
    cid[c] = myc;
    __syncthreads();
    int rank = 0;
    for (int t2 = 0; t2 < c; ++t2) rank += (cid[t2] == myc) ? 1 : 0;
    const int slot = lbase[myc] + rank;
    float4 o; o.x = px; o.y = py; o.z = vel[2 * i]; o.w = vel[2 * i + 1];
    sorted4[slot] = o;
    sidx[slot]    = i;
}

__device__ __forceinline__ void finalize_core(
    float vix, float viy, const f32x2 nz,
    float ws, float wa, float wc, float wn,
    float sx, float sy, float vx, float vy, float cx, float cy, float cntall,
    float* __restrict__ out, int orig)
{
    const float cnt = cntall - 1.0f;  // remove self (d2==0 passed the mask)
    float ns  = fmaxf(sqrtf(sx * sx + sy * sy), EPSF);
    float ssx = sx / ns, ssy = sy / ns;
    float vax = (vx - vix) / cnt - vix;
    float vay = (vy - viy) / cnt - viy;
    float na  = fmaxf(sqrtf(vax * vax + vay * vay), EPSF);
    float sax = vax / na, say = vay / na;
    float pax = cx / cnt, pay = cy / cnt;
    float nc  = fmaxf(sqrtf(pax * pax + pay * pay), EPSF);
    float scx = pax / nc, scy = pay / nc;
    float ax = ws * ssx + wa * sax + wc * scx;
    float ay = ws * ssy + wa * say + wc * scy;
    ax += wn * nz.x;
    ay += wn * nz.y;
    const float nn = sqrtf(ax * ax + ay * ay);
    if (nn > 1.0f) {
        const float s = 1.0f / fmaxf(nn, EPSF);
        ax *= s;
        ay *= s;
    }
    out[2 * orig]     = ax;
    out[2 * orig + 1] = ay;
}

// ---- main kernel: ONE sorted i-boid per wave, neighborhood-limited j loop
__global__ __launch_bounds__(256, 8) void boids_main(
    const float4* __restrict__ sorted4,
    const int* __restrict__ sidx,
    const int* __restrict__ cs,
    const f32x2* __restrict__ noise,
    const float* __restrict__ w_sep,
    const float* __restrict__ w_ali,
    const float* __restrict__ w_coh,
    const float* __restrict__ w_noise,
    float* __restrict__ out)
{
    __shared__ int cs_l[NCELL + 1];
    const int tid = threadIdx.x;
    cs_l[tid] = cs[tid];
    if (tid == 0) cs_l[NCELL] = cs[NCELL];
    __syncthreads();

    const int lane = tid & 63;
    const int wid  = tid >> 6;
    const int si   = blockIdx.x * 4 + wid;   // sorted boid index

    const float4 I0 = sorted4[si];
    const float vperc = PERC_R2;
    const float vsep  = SEP_R2;

    // perception box -> cell ranges (wrap via &15)
    const int cx0 = (int)floorf((I0.x - MARG) * 16.0f);
    const int cx1 = (int)floorf((I0.x + MARG) * 16.0f);
    const int cy0 = (int)floorf((I0.y - MARG) * 16.0f);
    const int cy1 = (int)floorf((I0.y + MARG) * 16.0f);
    int nx = cx1 - cx0 + 1; if (nx > NC) nx = NC;
    int ny = cy1 - cy0 + 1; if (ny > NC) ny = NC;
    const int a0 = cx0 & (NC - 1);
    const int lenA = (nx < NC - a0) ? nx : (NC - a0);
    const int lenB = nx - lenA;

    float n0 = 0.f, s0x = 0.f, s0y = 0.f, v0x = 0.f, v0y = 0.f, c0x = 0.f, c0y = 0.f;

    for (int r = 0; r < ny; ++r) {
        const int ry      = (cy0 + r) & (NC - 1);
        const int rowbase = ry * NC;
        const int sA = cs_l[rowbase + a0];
        const int eA = cs_l[rowbase + a0 + lenA];
        const int sB = cs_l[rowbase];
        const int eB = cs_l[rowbase + lenB];   // lenB==0 -> sB==eB -> skipped
        for (int seg = 0; seg < 2; ++seg) {
            const int js = seg ? sB : sA;
            const int je = seg ? eB : eA;
            for (int j0 = js; j0 < je; j0 += 64) {
                const int   rem = je - j0;
                const int   jj  = (lane < rem) ? (j0 + lane) : j0;
                const float inv = (lane < rem) ? 0.0f : 1e9f;  // pad lanes fail masks
                const float4 q  = sorted4[jj];
                float dx, dy, ta, tb, m;
                asm(
                    "v_sub_f32   %[dx], %[qx], %[px]\n\t"
                    "v_sub_f32   %[dy], %[qy], %[py]\n\t"
                    "v_rndne_f32 %[ta], %[dx]\n\t"
                    "v_rndne_f32 %[tb], %[dy]\n\t"
                    "v_sub_f32   %[dx], %[dx], %[ta]\n\t"
                    "v_sub_f32   %[dy], %[dy], %[tb]\n\t"
                    "v_mul_f32   %[ta], %[dx], %[dx]\n\t"
                    "v_mul_f32   %[tb], %[dy], %[dy]\n\t"
                    "v_add_f32   %[ta], %[ta], %[tb]\n\t"   // d2 (exact RN)
                    "v_max_f32   %[ta], %[ta], %[inv]\n\t"  // pad -> 1e9
                    "v_cmp_ge_f32 vcc, %[vperc], %[ta]\n\t"
                    "v_cndmask_b32 %[m], 0, 1.0, vcc\n\t"
                    "v_add_f32   %[n0], %[n0], %[m]\n\t"
                    "v_fmac_f32  %[v0x], %[m], %[qz]\n\t"
                    "v_fmac_f32  %[v0y], %[m], %[qw]\n\t"
                    "v_fmac_f32  %[c0x], %[m], %[dx]\n\t"
                    "v_fmac_f32  %[c0y], %[m], %[dy]\n\t"
                    "v_cmp_ge_f32 vcc, %[vsep], %[ta]\n\t"
                    "v_cndmask_b32 %[m], 0, 1.0, vcc\n\t"
                    "v_fma_f32   %[s0x], -%[m], %[dx], %[s0x]\n\t"
                    "v_fma_f32   %[s0y], -%[m], %[dy], %[s0y]\n\t"
                    : [dx] "=&v"(dx), [dy] "=&v"(dy), [ta] "=&v"(ta),
                      [tb] "=&v"(tb), [m] "=&v"(m),
                      [n0] "+v"(n0), [s0x] "+v"(s0x), [s0y] "+v"(s0y),
                      [v0x] "+v"(v0x), [v0y] "+v"(v0y),
                      [c0x] "+v"(c0x), [c0y] "+v"(c0y)
                    : [qx] "v"(q.x), [qy] "v"(q.y), [qz] "v"(q.z), [qw] "v"(q.w),
                      [px] "v"(I0.x), [py] "v"(I0.y),
                      [vperc] "v"(vperc), [vsep] "v"(vsep), [inv] "v"(inv)
                    : "vcc");
            }
        }
    }

    // full-wave butterfly reduction
#pragma unroll
    for (int mlev = 1; mlev < 64; mlev <<= 1) {
        n0  += __shfl_xor(n0,  mlev);
        s0x += __shfl_xor(s0x, mlev);  s0y += __shfl_xor(s0y, mlev);
        v0x += __shfl_xor(v0x, mlev);  v0y += __shfl_xor(v0y, mlev);
        c0x += __shfl_xor(c0x, mlev);  c0y += __shfl_xor(c0y, mlev);
    }

    if (lane == 0) {
        const int orig = sidx[si];
        finalize_core(I0.z, I0.w, noise[orig],
                      w_sep[0], w_ali[0], w_coh[0], w_noise[0],
                      s0x, s0y, v0x, v0y, c0x, c0y, n0, out, orig);
    }
}

// ================= fallback: proven R5 all-pairs kernel =================
constexpr int FB_BLOCK = 256;
constexpr int FB_TILE  = 2048;

__global__ __launch_bounds__(FB_BLOCK, 4) void boids_allpairs(
    const f32x2* __restrict__ pos, const f32x2* __restrict__ vel,
    const f32x2* __restrict__ noise,
    const float* __restrict__ w_sep, const float* __restrict__ w_ali,
    const float* __restrict__ w_coh, const float* __restrict__ w_noise,
    float* __restrict__ out)
{
    __shared__ f32x4 tile[FB_TILE];
    const int tid  = threadIdx.x;
    const int lane = tid & 63;
    const int wid  = tid >> 6;
    const int i0   = (blockIdx.x * 4 + wid) * 2;
    const f32x2 P0 = pos[i0];
    const f32x2 P1 = pos[i0 + 1];
    const float vperc = PERC_R2, vsep = SEP_R2;
    float n0 = 0.f, s0x = 0.f, s0y = 0.f, v0x = 0.f, v0y = 0.f, c0x = 0.f, c0y = 0.f;
    float n1 = 0.f, s1x = 0.f, s1y = 0.f, v1x = 0.f, v1y = 0.f, c1x = 0.f, c1y = 0.f;
    for (int t = 0; t < N_BOIDS / FB_TILE; ++t) {
        const f32x4* gp = reinterpret_cast<const f32x4*>(pos) + t * (FB_TILE / 2);
        const f32x4* gv = reinterpret_cast<const f32x4*>(vel) + t * (FB_TILE / 2);
#pragma unroll
        for (int c = 0; c < FB_TILE / 2 / FB_BLOCK; ++c) {
            const int idx  = tid + c * FB_BLOCK;
            const f32x4 pp = gp[idx];
            const f32x4 vv = gv[idx];
            f32x4 t0; t0.x = pp.x; t0.y = pp.y; t0.z = vv.x; t0.w = vv.y;
            f32x4 t1; t1.x = pp.z; t1.y = pp.w; t1.z = vv.z; t1.w = vv.w;
            tile[2 * idx] = t0; tile[2 * idx + 1] = t1;
        }
        __syncthreads();
#pragma unroll 8
        for (int k = 0; k < FB_TILE / 64; ++k) {
            const f32x4 q = tile[lane + k * 64];
            float dx, dy, ta, tb, m;
            asm("v_sub_f32 %[dx], %[qx], %[p0x]\n\t"
                "v_sub_f32 %[dy], %[qy], %[p0y]\n\t"
                "v_rndne_f32 %[ta], %[dx]\n\t"
                "v_rndne_f32 %[tb], %[dy]\n\t"
                "v_sub_f32 %[dx], %[dx], %[ta]\n\t"
                "v_sub_f32 %[dy], %[dy], %[tb]\n\t"
                "v_mul_f32 %[ta], %[dx], %[dx]\n\t"
                "v_mul_f32 %[tb], %[dy], %[dy]\n\t"
                "v_add_f32 %[ta], %[ta], %[tb]\n\t"
                "v_cmp_ge_f32 vcc, %[vperc], %[ta]\n\t"
                "v_cndmask_b32 %[m], 0, 1.0, vcc\n\t"
                "v_add_f32 %[n0], %[n0], %[m]\n\t"
                "v_fmac_f32 %[v0x], %[m], %[qz]\n\t"
                "v_fmac_f32 %[v0y], %[m], %[qw]\n\t"
                "v_fmac_f32 %[c0x], %[m], %[dx]\n\t"
                "v_fmac_f32 %[c0y], %[m], %[dy]\n\t"
                "v_cmp_ge_f32 vcc, %[vsep], %[ta]\n\t"
                "v_cndmask_b32 %[m], 0, 1.0, vcc\n\t"
                "v_fma_f32 %[s0x], -%[m], %[dx], %[s0x]\n\t"
                "v_fma_f32 %[s0y], -%[m], %[dy], %[s0y]\n\t"
                "v_sub_f32 %[dx], %[qx], %[p1x]\n\t"
                "v_sub_f32 %[dy], %[qy], %[p1y]\n\t"
                "v_rndne_f32 %[ta], %[dx]\n\t"
                "v_rndne_f32 %[tb], %[dy]\n\t"
                "v_sub_f32 %[dx], %[dx], %[ta]\n\t"
                "v_sub_f32 %[dy], %[dy], %[tb]\n\t"
                "v_mul_f32 %[ta], %[dx], %[dx]\n\t"
                "v_mul_f32 %[tb], %[dy], %[dy]\n\t"
                "v_add_f32 %[ta], %[ta], %[tb]\n\t"
                "v_cmp_ge_f32 vcc, %[vperc], %[ta]\n\t"
                "v_cndmask_b32 %[m], 0, 1.0, vcc\n\t"
                "v_add_f32 %[n1], %[n1], %[m]\n\t"
                "v_fmac_f32 %[v1x], %[m], %[qz]\n\t"
                "v_fmac_f32 %[v1y], %[m], %[qw]\n\t"
                "v_fmac_f32 %[c1x], %[m], %[dx]\n\t"
                "v_fmac_f32 %[c1y], %[m], %[dy]\n\t"
                "v_cmp_ge_f32 vcc, %[vsep], %[ta]\n\t"
                "v_cndmask_b32 %[m], 0, 1.0, vcc\n\t"
                "v_fma_f32 %[s1x], -%[m], %[dx], %[s1x]\n\t"
                "v_fma_f32 %[s1y], -%[m], %[dy], %[s1y]\n\t"
                : [dx] "=&v"(dx), [dy] "=&v"(dy), [ta] "=&v"(ta),
                  [tb] "=&v"(tb), [m] "=&v"(m),
                  [n0] "+v"(n0), [s0x] "+v"(s0x), [s0y] "+v"(s0y),
                  [v0x] "+v"(v0x), [v0y] "+v"(v0y), [c0x] "+v"(c0x), [c0y] "+v"(c0y),
                  [n1] "+v"(n1), [s1x] "+v"(s1x), [s1y] "+v"(s1y),
                  [v1x] "+v"(v1x), [v1y] "+v"(v1y), [c1x] "+v"(c1x), [c1y] "+v"(c1y)
                : [qx] "v"(q.x), [qy] "v"(q.y), [qz] "v"(q.z), [qw] "v"(q.w),
                  [p0x] "v"(P0.x), [p0y] "v"(P0.y),
                  [p1x] "v"(P1.x), [p1y] "v"(P1.y),
                  [vperc] "v"(vperc), [vsep] "v"(vsep)
                : "vcc");
        }
        __syncthreads();
    }
#pragma unroll
    for (int mlev = 1; mlev < 64; mlev <<= 1) {
        n0  += __shfl_xor(n0,  mlev);
        s0x += __shfl_xor(s0x, mlev);  s0y += __shfl_xor(s0y, mlev);
        v0x += __shfl_xor(v0x, mlev);  v0y += __shfl_xor(v0y, mlev);
        c0x += __shfl_xor(c0x, mlev);  c0y += __shfl_xor(c0y, mlev);
        n1  += __shfl_xor(n1,  mlev);
        s1x += __shfl_xor(s1x, mlev);  s1y += __shfl_xor(s1y, mlev);
        v1x += __shfl_xor(v1x, mlev);  v1y += __shfl_xor(v1y, mlev);
        c1x += __shfl_xor(c1x, mlev);  c1y += __shfl_xor(c1y, mlev);
    }
    if (lane < 2) {
        float sx = s0x, sy = s0y, vx = v0x, vy = v0y, cx = c0x, cy = c0y, cc = n0;
        int i = i0;
        if (lane == 1) {
            sx = s1x; sy = s1y; vx = v1x; vy = v1y; cx = c1x; cy = c1y; cc = n1;
            i = i0 + 1;
        }
        finalize_core(vel[i].x, vel[i].y, noise[i],
                      w_sep[0], w_ali[0], w_coh[0], w_noise[0],
                      sx, sy, vx, vy, cx, cy, cc, out, i);
    }
}

extern "C" void kernel_launch(void* const* d_in, const int* in_sizes, int n_in,
                              void* d_out, int out_size, void* d_ws, size_t ws_size,
                              hipStream_t stream) {
    const float* pos_f   = (const float*)d_in[0];
    const float* vel_f   = (const float*)d_in[1];
    const f32x2* noise   = (const f32x2*)d_in[2];
    const float* w_sep   = (const float*)d_in[3];
    const float* w_ali   = (const float*)d_in[4];
    const float* w_coh   = (const float*)d_in[5];
    const float* w_noise = (const float*)d_in[6];
    float* out = (float*)d_out;

    if (ws_size >= WS_NEED) {
        char* wsb = (char*)d_ws;
        int*    hist    = (int*)(wsb + HIST_OFF);
        int*    cs      = (int*)(wsb + CS_OFF);
        float4* sorted4 = (float4*)(wsb + SORT_OFF);
        int*    sidx    = (int*)(wsb + SIDX_OFF);
        cell_hist<<<NBLK, CHUNK, 0, stream>>>(pos_f, hist);
        cell_scan_scatter<<<NBLK, CHUNK, 0, stream>>>(pos_f, vel_f, hist, cs,
                                                      sorted4, sidx);
        boids_main<<<N_BOIDS / 4, 256, 0, stream>>>(
            sorted4, sidx, cs, noise, w_sep, w_ali, w_coh, w_noise, out);
    } else {
        boids_allpairs<<<N_BOIDS / 8, FB_BLOCK, 0, stream>>>(
            (const f32x2*)pos_f, (const f32x2*)vel_f, noise,
            w_sep, w_ali, w_coh, w_noise, out);
    }
}